// Round 3
// baseline (210.966 us; speedup 1.0000x reference)
//
#include <hip/hip_runtime.h>
#include <math.h>

// Problem constants
#define BB 8
#define CC 64
#define HH 128
#define WW 128
#define KK 6

// Workspace layout (float offsets). Total 1,187,904 floats = 4.75 MB.
#define FEAT_OFF 0                      // [B][1024]
#define TH_OFF   8192                   // [B][6]  (sorted angles in radians)
#define COEF_OFF 8256                   // [N=48][C=64][S=2][H=128] = 786432
#define S_OFF    (8256 + 786432)        // [B][64][128][6] = post-affine S

// Radon LDS geometry: image rows/cols -2..129 (2-px zero border), stride 136.
// 136 mod 32 = 8 -> lane bank drift = 8*co+si (N) / 8*si+co (T).
#define STR  136
#define NROW 132
#define IMG_SZ (NROW * STR)            // 17952 floats
#define N_OFF 0
#define T_OFF IMG_SZ
#define SIG_OFF (2 * IMG_SZ)           // 768 floats
#define LDS_TOT (2 * IMG_SZ + 768)     // 36672 floats = 146.7 KB

// ---------------------------------------------------------------------------
// Kernel 1: adaptive avg-pool 4x4 -> feat[b, c*16 + i*4 + j]
// ---------------------------------------------------------------------------
__global__ __launch_bounds__(256) void k_pool(const float* __restrict__ x,
                                              float* __restrict__ ws) {
    int bc = blockIdx.x;               // b*64 + c
    int b = bc >> 6, c = bc & 63;
    int t = threadIdx.x;
    __shared__ float pool_l[16];
    if (t < 16) pool_l[t] = 0.f;
    __syncthreads();
    const float4* img4 = (const float4*)(x + (size_t)bc * 16384);
    float acc[4] = {0.f, 0.f, 0.f, 0.f};
    int cb = (t & 31) >> 3;            // W-block (32 float4 per row, 8 per block)
    #pragma unroll
    for (int r = 0; r < 16; ++r) {
        float4 v = img4[r * 256 + t];
        acc[r >> 2] += (v.x + v.y) + (v.z + v.w);
    }
    #pragma unroll
    for (int rb = 0; rb < 4; ++rb)
        atomicAdd(&pool_l[rb * 4 + cb], acc[rb]);
    __syncthreads();
    if (t < 16)
        ws[FEAT_OFF + b * 1024 + c * 16 + t] = pool_l[t] * (1.0f / 1024.0f);
}

// ---------------------------------------------------------------------------
// Kernel 2: MLP -> offsets -> clip -> sort -> radians. one block per b.
// ---------------------------------------------------------------------------
__global__ __launch_bounds__(256) void k_mlp(const float* __restrict__ lin1_w,
                                             const float* __restrict__ lin1_b,
                                             const float* __restrict__ lin2_w,
                                             const float* __restrict__ lin2_b,
                                             float* __restrict__ ws) {
    int b = blockIdx.x;
    int t = threadIdx.x;
    __shared__ float feat_l[1024];
    __shared__ float h_l[32];
    __shared__ float ang_l[6];
    const float* feat = ws + FEAT_OFF + b * 1024;
    for (int i = t; i < 1024; i += 256) feat_l[i] = feat[i];
    __syncthreads();
    int m = t >> 3, part = t & 7;
    const float* wrow = lin1_w + m * 1024 + part * 128;
    const float* frow = feat_l + part * 128;
    float acc = 0.f;
    #pragma unroll 8
    for (int i = 0; i < 128; ++i) acc = fmaf(frow[i], wrow[i], acc);
    acc += __shfl_xor(acc, 1);
    acc += __shfl_xor(acc, 2);
    acc += __shfl_xor(acc, 4);
    if (part == 0) h_l[m] = fmaxf(acc + lin1_b[m], 0.f);
    __syncthreads();
    if (t < 6) {
        float a = lin2_b[t];
        #pragma unroll
        for (int i = 0; i < 32; ++i) a = fmaf(h_l[i], lin2_w[t * 32 + i], a);
        a = 36.0f * (float)t + a * 30.0f;          // base = linspace(0,180,6)
        ang_l[t] = fminf(fmaxf(a, 0.f), 180.f);
    }
    __syncthreads();
    if (t == 0) {
        float v[6];
        #pragma unroll
        for (int i = 0; i < 6; ++i) v[i] = ang_l[i];
        for (int i = 1; i < 6; ++i) {              // insertion sort
            float key = v[i]; int j = i - 1;
            while (j >= 0 && v[j] > key) { v[j + 1] = v[j]; --j; }
            v[j + 1] = key;
        }
        #pragma unroll
        for (int i = 0; i < 6; ++i)
            ws[TH_OFF + b * 6 + i] = v[i] * (3.14159265358979323846f / 180.0f);
    }
}

// ---------------------------------------------------------------------------
// Bit-sliced max-multiplicity sim: how many of 64 lanes land on the most
// popular LDS bank if lane i sits at address ~ i*drift. Saturates at 8.
// ---------------------------------------------------------------------------
__device__ __forceinline__ int sim_mult(float drift) {
    unsigned c0 = 0, c1 = 0, c2 = 0, sat = 0;
    for (int i = 0; i < 64; ++i) {
        int bk = ((int)floorf(drift * (float)i + 0.5f)) & 31;
        unsigned m = 1u << bk;
        unsigned t0 = c0 & m;  c0 ^= m;
        unsigned t1 = c1 & t0; c1 ^= t0;
        unsigned t2 = c2 & t1; c2 ^= t1;
        sat |= t2;
    }
    int best = 0;
    for (int bk = 0; bk < 32; ++bk) {
        int mm = ((c0 >> bk) & 1) | (((c1 >> bk) & 1) << 1)
               | (((c2 >> bk) & 1) << 2) | (((sat >> bk) & 1) << 3);
        best = max(best, mm);
    }
    return best;
}

// ---------------------------------------------------------------------------
// Kernel 3: fused Radon + Wavelet. 384 threads (6 waves), 1 block/CU.
// Image held in LDS in BOTH row-major (N) and transposed (T) layouts with
// 2-px zero borders; per angle the layout with the lower simulated bank
// multiplicity is used (wave-uniform choice: each wave's 64 lines share k).
// Out-of-range samples are made exactly zero by clamping (iu,iv) into
// [-2,128]: both taps then land in zero rows/cols == padding_mode='zeros'.
// Loop bounds are wave-uniform (shuffle-reduced slab hints) -> no divergence.
// ---------------------------------------------------------------------------
__global__ __launch_bounds__(384) void k_radon(const float* __restrict__ x,
                                               const float* __restrict__ wf0,
                                               const float* __restrict__ wf1,
                                               float* __restrict__ ws) {
    int bc = blockIdx.x;
    int b = bc >> 6, c = bc & 63;
    int t = threadIdx.x;
    __shared__ float S[LDS_TOT];
    __shared__ float co_l[6], si_l[6];
    __shared__ int   sel_l[6];

    // zero the whole N image region (incl. borders + dead pad cols)
    for (int i = t; i < IMG_SZ; i += 384) S[N_OFF + i] = 0.f;
    __syncthreads();
    // stage interior: img row y -> lds row y+2, col x+2
    const float4* src4 = (const float4*)(x + (size_t)bc * 16384);
    for (int i = t; i < 4096; i += 384) {
        float4 v = src4[i];
        float* d = S + N_OFF + ((i >> 5) + 2) * STR + ((i & 31) << 2) + 2;
        d[0] = v.x; d[1] = v.y; d[2] = v.z; d[3] = v.w;
    }
    if (t < 6) {
        float th = ws[TH_OFF + b * 6 + t];
        float co = cosf(th), si = sinf(th);
        co_l[t] = co; si_l[t] = si;
        int mN = sim_mult(fmaf(136.f, co, si));    // N-layout lane drift
        int mT = sim_mult(fmaf(136.f, si, co));    // T-layout lane drift
        sel_l[t] = (mT < mN) ? 1 : 0;
    }
    __syncthreads();
    // build transposed copy (LDS->LDS; borders copied too). read drift 1
    // (clean), write drift 136 -> 4-way on a tiny number of instructions.
    for (int j = t; j < NROW * NROW; j += 384) {
        int yy = j / NROW, xx = j - yy * NROW;
        S[T_OFF + xx * STR + yy] = S[N_OFF + yy * STR + xx];
    }
    __syncthreads();

    // --- Radon: 768 (k,h) lines, 2 per thread, k wave-uniform per pass ---
    #pragma unroll
    for (int pass = 0; pass < 2; ++pass) {
        int p = pass * 384 + t;
        int k = p >> 7, h = p & 127;
        float co = co_l[k], si = si_l[k];
        int sel = sel_l[k];
        float yc = fmaf((float)h, 2.0f / 127.0f, -1.0f);
        float ix0 = (fmaf(yc, si, -co) + 1.0f) * 63.5f;  // d(ix)/dw = co
        float iy0 = (fmaf(yc, co,  si) + 1.0f) * 63.5f;  // d(iy)/dw = -si
        // unified coords: u = row coordinate of chosen layout, v = col
        float u0 = sel ? ix0 : iy0;
        float v0 = sel ? iy0 : ix0;
        float du = sel ? co  : -si;
        float dv = sel ? -si : co;
        int abase = (sel ? T_OFF : N_OFF) + 2 * STR + 2;

        // slab hint for {w : u,v in [-1,128]} (safety from clamping, so this
        // only needs to be roughly right; NaN/inf degrade to loose bounds)
        float idu = 1.0f / du, idv = 1.0f / dv;
        float a1 = (-1.0f - u0) * idu, a2 = (128.0f - u0) * idu;
        float b1 = (-1.0f - v0) * idv, b2 = (128.0f - v0) * idv;
        float wlo = fmaxf(fminf(a1, a2), fminf(b1, b2));
        float whi = fminf(fmaxf(a1, a2), fmaxf(b1, b2));
        int wAl = min(max((int)floorf(wlo), 0), 128);
        int wBl = min(max((int)ceilf(whi), 0), 127);
        // wave-uniform bounds: min/max across all 64 lanes
        #pragma unroll
        for (int sft = 1; sft < 64; sft <<= 1) {
            wAl = min(wAl, __shfl_xor(wAl, sft));
            wBl = max(wBl, __shfl_xor(wBl, sft));
        }
        int wA = max(wAl - 1, 0);
        int wE = min(wBl + 2, 128);

        float acc = 0.f;
        #pragma unroll 2
        for (int w = wA; w < wE; ++w) {
            float fw = (float)w;
            float u = fmaf(fw, du, u0);
            float v = fmaf(fw, dv, v0);
            float fu = floorf(u), fv = floorf(v);
            float wu = u - fu, wv = v - fv;
            int iu = (int)fu, iv = (int)fv;
            iu = min(max(iu, -2), 128);            // v_med3_i32
            iv = min(max(iv, -2), 128);
            int idx = abase + iu * STR + iv;
            float q0 = S[idx],       q1 = S[idx + 1];        // ds_read2
            float q2 = S[idx + STR], q3 = S[idx + STR + 1];  // ds_read2
            float r0 = fmaf(wv, q1 - q0, q0);
            float r1 = fmaf(wv, q3 - q2, q2);
            acc += fmaf(wu, r1 - r0, r0);
        }
        S[SIG_OFF + p] = acc;
    }
    __syncthreads();

    // --- Wavelet chain on sig (6 rows of 128). Scratch overlays N image. ---
    const float* sigl = S + SIG_OFF;
    float* cur = S + N_OFF;          // 6*64
    float* f1  = S + N_OFF + 384;    // 6*64
    float* p1  = S + N_OFF + 768;    // 6*32
    float* u1  = S + N_OFF + 960;    // 6*64
    float g0 = wf0[0], g1 = wf0[1], g2 = wf0[2];

    for (int p = t; p < 768; p += 384) {           // c0 = conv3(sig)
        int k = p >> 7, h = p & 127;
        const float* s = sigl + k * 128;
        float sm1 = (h > 0)   ? s[h - 1] : 0.f;
        float sp1 = (h < 127) ? s[h + 1] : 0.f;
        float c0 = sm1 * g0 + s[h] * g1 + sp1 * g2;
        ws[COEF_OFF + (((b * 6 + k) * 64 + c) * 2 + 0) * 128 + h] = c0;
    }
    for (int q = t; q < 384; q += 384) {           // cur = avgpool(sig)
        int k = q >> 6, l = q & 63;
        cur[q] = (sigl[k * 128 + 2 * l] + sigl[k * 128 + 2 * l + 1]) * 0.5f;
    }
    __syncthreads();

    float w10 = wf1[0], w11 = wf1[1], w12 = wf1[2], w13 = wf1[3], w14 = wf1[4];
    for (int q = t; q < 384; q += 384) {           // f1 = conv5(cur)
        int k = q >> 6, l = q & 63;
        const float* cu = cur + k * 64;
        float a = cu[l] * w12;
        a += (l >= 2)  ? cu[l - 2] * w10 : 0.f;
        a += (l >= 1)  ? cu[l - 1] * w11 : 0.f;
        a += (l <= 62) ? cu[l + 1] * w13 : 0.f;
        a += (l <= 61) ? cu[l + 2] * w14 : 0.f;
        f1[q] = a;
    }
    __syncthreads();

    for (int q = t; q < 192; q += 384) {           // p1 = avgpool(f1)
        int k = q >> 5, m = q & 31;
        p1[q] = (f1[k * 64 + 2 * m] + f1[k * 64 + 2 * m + 1]) * 0.5f;
    }
    __syncthreads();

    for (int q = t; q < 384; q += 384) {           // u1 = interp(p1: 32->64)
        int k = q >> 6, l = q & 63;
        float real = fminf(fmaxf(0.5f * (float)l - 0.25f, 0.f), 31.f);
        int i0 = (int)real;
        int i1 = min(i0 + 1, 31);
        float wv = real - (float)i0;
        u1[q] = p1[k * 32 + i0] * (1.f - wv) + p1[k * 32 + i1] * wv;
    }
    __syncthreads();

    for (int p = t; p < 768; p += 384) {           // c1 = interp(u1: 64->128)
        int k = p >> 7, h = p & 127;
        float real = fminf(fmaxf(0.5f * (float)h - 0.25f, 0.f), 63.f);
        int i0 = (int)real;
        int i1 = min(i0 + 1, 63);
        float wv = real - (float)i0;
        float c1 = u1[k * 64 + i0] * (1.f - wv) + u1[k * 64 + i1] * wv;
        ws[COEF_OFF + (((b * 6 + k) * 64 + c) * 2 + 1) * 128 + h] = c1;
    }
}

// ---------------------------------------------------------------------------
// Kernel 4: fusion GEMM hoisted before the k->W interp (linearity), permutation
// undone at staging, bias+BN folded. grid = 48*4 (quarter of o-range each).
// ---------------------------------------------------------------------------
__global__ __launch_bounds__(256) void k_fuse(const float* __restrict__ fuse_w,
                                              const float* __restrict__ fuse_b,
                                              const float* __restrict__ bn_gamma,
                                              const float* __restrict__ bn_beta,
                                              const float* __restrict__ bn_mean,
                                              const float* __restrict__ bn_var,
                                              float* __restrict__ ws) {
    int blk = blockIdx.x;
    int n = blk >> 2, q = blk & 3;    // n = b*6 + k
    int b = n / 6, k = n - b * 6;
    int t = threadIdx.x;
    __shared__ __align__(16) float M[128 * 128];   // 64 KB, M[c2][h2]
    __shared__ float w_l[16 * 128];                // 8 KB
    const float* coef = ws + COEF_OFF + n * 16384;
    for (int i = t; i < 16384; i += 256) {
        int cc = i >> 8, rem = i & 255, s = rem >> 7, hpos = rem & 127;
        int c2 = 2 * cc + (hpos >> 6);
        int h2 = ((hpos & 63) << 1) | s;
        M[c2 * 128 + h2] = coef[i];
    }
    for (int i = t; i < 2048; i += 256)
        w_l[i] = fuse_w[(q * 16 + (i >> 7)) * 128 + (i & 127)];
    __syncthreads();

    int hg = t & 31;                  // h2 base = hg*4
    int og = t >> 5;                  // o pair index 0..7
    float acc[2][4];
    #pragma unroll
    for (int oo = 0; oo < 2; ++oo)
        #pragma unroll
        for (int j = 0; j < 4; ++j) acc[oo][j] = 0.f;

    const float* w0 = w_l + (og * 2) * 128;
    const float* w1 = w0 + 128;
    for (int c2 = 0; c2 < 128; ++c2) {
        float4 m4 = *(const float4*)(M + c2 * 128 + (hg << 2));
        float a0 = w0[c2], a1 = w1[c2];
        acc[0][0] = fmaf(a0, m4.x, acc[0][0]);
        acc[0][1] = fmaf(a0, m4.y, acc[0][1]);
        acc[0][2] = fmaf(a0, m4.z, acc[0][2]);
        acc[0][3] = fmaf(a0, m4.w, acc[0][3]);
        acc[1][0] = fmaf(a1, m4.x, acc[1][0]);
        acc[1][1] = fmaf(a1, m4.y, acc[1][1]);
        acc[1][2] = fmaf(a1, m4.z, acc[1][2]);
        acc[1][3] = fmaf(a1, m4.w, acc[1][3]);
    }
    #pragma unroll
    for (int oo = 0; oo < 2; ++oo) {
        int o = q * 16 + og * 2 + oo;
        float scale = bn_gamma[o] * rsqrtf(bn_var[o] + 1e-5f);
        float shift = (fuse_b[o] - bn_mean[o]) * scale + bn_beta[o];
        int basei = ((b * 64 + o) * 128 + hg * 4) * 6 + k;
        #pragma unroll
        for (int j = 0; j < 4; ++j)
            ws[S_OFF + basei + j * 6] = fmaf(acc[oo][j], scale, shift);
    }
}

// ---------------------------------------------------------------------------
// Kernel 5: k(6) -> w(128) align_corners=True interp + ReLU + store.
// ---------------------------------------------------------------------------
__global__ __launch_bounds__(256) void k_out(const float* __restrict__ Sg,
                                             float* __restrict__ out) {
    int idx = blockIdx.x * 256 + threadIdx.x;    // (b,o,h2,w)
    int w = idx & 127;
    int row = idx >> 7;
    float pos = (float)w * (5.0f / 127.0f);
    int i0 = min((int)pos, 5);
    int i1 = min(i0 + 1, 5);
    float tt = pos - (float)i0;
    const float* srow = Sg + row * 6;
    float val = srow[i0] * (1.f - tt) + srow[i1] * tt;
    out[idx] = fmaxf(val, 0.f);
}

// ---------------------------------------------------------------------------
extern "C" void kernel_launch(void* const* d_in, const int* in_sizes, int n_in,
                              void* d_out, int out_size, void* d_ws, size_t ws_size,
                              hipStream_t stream) {
    const float* x        = (const float*)d_in[0];
    const float* lin1_w   = (const float*)d_in[1];
    const float* lin1_b   = (const float*)d_in[2];
    const float* lin2_w   = (const float*)d_in[3];
    const float* lin2_b   = (const float*)d_in[4];
    const float* wf0      = (const float*)d_in[5];
    const float* wf1      = (const float*)d_in[6];
    const float* fuse_w   = (const float*)d_in[7];
    const float* fuse_b   = (const float*)d_in[8];
    const float* bn_gamma = (const float*)d_in[9];
    const float* bn_beta  = (const float*)d_in[10];
    const float* bn_mean  = (const float*)d_in[11];
    const float* bn_var   = (const float*)d_in[12];
    float* ws  = (float*)d_ws;        // needs 4.75 MB
    float* out = (float*)d_out;

    hipLaunchKernelGGL(k_pool,  dim3(BB * CC), dim3(256), 0, stream, x, ws);
    hipLaunchKernelGGL(k_mlp,   dim3(BB),      dim3(256), 0, stream,
                       lin1_w, lin1_b, lin2_w, lin2_b, ws);
    hipLaunchKernelGGL(k_radon, dim3(BB * CC), dim3(384), 0, stream, x, wf0, wf1, ws);
    hipLaunchKernelGGL(k_fuse,  dim3(BB * KK * 4), dim3(256), 0, stream,
                       fuse_w, fuse_b, bn_gamma, bn_beta, bn_mean, bn_var, ws);
    hipLaunchKernelGGL(k_out,   dim3((BB * CC * HH * WW) / 256), dim3(256), 0, stream,
                       ws + S_OFF, out);
}

// Round 4
// 181.294 us; speedup vs baseline: 1.1637x; 1.1637x over previous
//
#include <hip/hip_runtime.h>
#include <math.h>

// Problem constants
#define BB 8
#define CC 64
#define HH 128
#define WW 128
#define KK 6

// Workspace layout (float offsets). Total 794,688 floats = 3.18 MB.
#define FEAT_OFF 0                      // [B][1024]
#define COEF_OFF 8192                   // [N=48][C=64][S=2][H=128] = 786432

// Radon LDS geometry: rows/cols -2..129 (2-px zero border), stride 133.
// 133 mod 32 = 5 -> lane bank drift = 5co+si: clean at all 6 base angles
// (0:5, 36:12.2, 72:10.1, 108:-8.2, 144:-11, 180:-5  mod 32).
#define STR  133
#define NROW 132
#define IMG_SZ (NROW * STR)            // 17556 floats = 70.2 KB

// ---------------------------------------------------------------------------
// Kernel 1: adaptive avg-pool 4x4 -> feat[b, c*16 + i*4 + j]
// ---------------------------------------------------------------------------
__global__ __launch_bounds__(256) void k_pool(const float* __restrict__ x,
                                              float* __restrict__ ws) {
    int bc = blockIdx.x;               // b*64 + c
    int b = bc >> 6, c = bc & 63;
    int t = threadIdx.x;
    __shared__ float pool_l[16];
    if (t < 16) pool_l[t] = 0.f;
    __syncthreads();
    const float4* img4 = (const float4*)(x + (size_t)bc * 16384);
    float acc[4] = {0.f, 0.f, 0.f, 0.f};
    int cb = (t & 31) >> 3;            // W-block (32 float4 per row, 8 per block)
    #pragma unroll
    for (int r = 0; r < 16; ++r) {
        float4 v = img4[r * 256 + t];
        acc[r >> 2] += (v.x + v.y) + (v.z + v.w);
    }
    #pragma unroll
    for (int rb = 0; rb < 4; ++rb)
        atomicAdd(&pool_l[rb * 4 + cb], acc[rb]);
    __syncthreads();
    if (t < 16)
        ws[FEAT_OFF + b * 1024 + c * 16 + t] = pool_l[t] * (1.0f / 1024.0f);
}

// ---------------------------------------------------------------------------
// Kernel 2: fused MLP (angles) + Radon + Wavelet. One block per (b,c),
// 256 threads, ~77.6 KB LDS -> 2 blocks/CU. The MLP is recomputed per block
// (deterministic; lin1_w 128KB stays L2-hot) to remove a kernel launch.
// Bilinear taps: 2-px zero border + med3 clamp of (iu,iv) into [-2,128]
// makes out-of-range samples exactly 0 (padding_mode='zeros'), so loop
// bounds are a wave-uniform perf hint only (shuffle-reduced slab).
// ---------------------------------------------------------------------------
__global__ __launch_bounds__(256) void k_radon(const float* __restrict__ x,
                                               const float* __restrict__ lin1_w,
                                               const float* __restrict__ lin1_b,
                                               const float* __restrict__ lin2_w,
                                               const float* __restrict__ lin2_b,
                                               const float* __restrict__ wf0,
                                               const float* __restrict__ wf1,
                                               float* __restrict__ ws) {
    int bc = blockIdx.x;
    int b = bc >> 6, c = bc & 63;
    int t = threadIdx.x;
    __shared__ float img[IMG_SZ];      // 70.2 KB
    __shared__ float sigl[768];        // [k][h]
    __shared__ float feat_l[1024];
    __shared__ float h_l[32];
    __shared__ float ang_l[6], ang_s[6];
    __shared__ float co_l[6], si_l[6];

    // --- zero border cells (no overlap with interior -> no race) ---
    for (int i = t; i < 2 * STR; i += 256) {       // rows 0,1 and 130,131
        img[i] = 0.f;
        img[130 * STR + i] = 0.f;
    }
    if (t < 128) {                                  // cols 0,1,130,131,132
        float* r = img + (t + 2) * STR;
        r[0] = 0.f; r[1] = 0.f; r[130] = 0.f; r[131] = 0.f; r[132] = 0.f;
    }
    // --- stage interior: img row y -> lds row y+2, col x+2 ---
    const float4* src4 = (const float4*)(x + (size_t)bc * 16384);
    for (int i = t; i < 4096; i += 256) {
        float4 v = src4[i];
        float* d = img + ((i >> 5) + 2) * STR + ((i & 31) << 2) + 2;
        d[0] = v.x; d[1] = v.y; d[2] = v.z; d[3] = v.w;
    }
    // --- inline MLP: feat -> angles ---
    const float* feat = ws + FEAT_OFF + b * 1024;
    for (int i = t; i < 1024; i += 256) feat_l[i] = feat[i];
    __syncthreads();
    {
        int m = t >> 3, part = t & 7;
        const float4* wrow = (const float4*)(lin1_w + m * 1024 + part * 128);
        const float4* frow = (const float4*)(feat_l + part * 128);
        float acc = 0.f;
        #pragma unroll 8
        for (int i = 0; i < 32; ++i) {
            float4 wv = wrow[i], fv = frow[i];
            acc = fmaf(wv.x, fv.x, acc); acc = fmaf(wv.y, fv.y, acc);
            acc = fmaf(wv.z, fv.z, acc); acc = fmaf(wv.w, fv.w, acc);
        }
        acc += __shfl_xor(acc, 1);
        acc += __shfl_xor(acc, 2);
        acc += __shfl_xor(acc, 4);
        if (part == 0) h_l[m] = fmaxf(acc + lin1_b[m], 0.f);
    }
    __syncthreads();
    if (t < 6) {
        float a = lin2_b[t];
        #pragma unroll
        for (int i = 0; i < 32; ++i) a = fmaf(h_l[i], lin2_w[t * 32 + i], a);
        a = 36.0f * (float)t + a * 30.0f;          // base = linspace(0,180,6)
        ang_l[t] = fminf(fmaxf(a, 0.f), 180.f);
    }
    __syncthreads();
    if (t == 0) {
        float v[6];
        #pragma unroll
        for (int i = 0; i < 6; ++i) v[i] = ang_l[i];
        for (int i = 1; i < 6; ++i) {              // insertion sort
            float key = v[i]; int j = i - 1;
            while (j >= 0 && v[j] > key) { v[j + 1] = v[j]; --j; }
            v[j + 1] = key;
        }
        #pragma unroll
        for (int i = 0; i < 6; ++i) ang_s[i] = v[i];
    }
    __syncthreads();
    if (t < 6) {
        float th = ang_s[t] * (3.14159265358979323846f / 180.0f);
        co_l[t] = cosf(th);
        si_l[t] = sinf(th);
    }
    __syncthreads();

    const float* base2 = img + 2 * STR + 2;   // (y,x) -> base2[y*STR+x], y,x in [-2,129]

    // --- Radon: 768 (k,h) lines, 3 per thread, k wave-uniform per pass ---
    for (int p = t; p < 768; p += 256) {
        int k = p >> 7, h = p & 127;
        float co = co_l[k], si = si_l[k];
        float yc = fmaf((float)h, 2.0f / 127.0f, -1.0f);
        float ix0 = (fmaf(yc, si, -co) + 1.0f) * 63.5f;  // d(ix)/dw = co
        float iy0 = (fmaf(yc, co,  si) + 1.0f) * 63.5f;  // d(iy)/dw = -si

        // slab hint for {w : ix,iy in [-1,128]} (clamping gives safety)
        float ic = 1.0f / co, is = 1.0f / (-si);
        float a1 = (-1.0f - ix0) * ic, a2 = (128.0f - ix0) * ic;
        float b1 = (-1.0f - iy0) * is, b2 = (128.0f - iy0) * is;
        float wlo = fmaxf(fminf(a1, a2), fminf(b1, b2));
        float whi = fminf(fmaxf(a1, a2), fmaxf(b1, b2));
        int wAl = (int)floorf(fminf(fmaxf(wlo, 0.f), 127.f));
        int wBl = (int)ceilf(fminf(fmaxf(whi, 0.f), 127.f));
        // wave-uniform bounds (min/max over 64 lanes) -> zero divergence
        #pragma unroll
        for (int sft = 1; sft < 64; sft <<= 1) {
            wAl = min(wAl, __shfl_xor(wAl, sft));
            wBl = max(wBl, __shfl_xor(wBl, sft));
        }
        int wA = max(wAl - 1, 0);
        int wE = min(wBl + 2, 128);

        float acc = 0.f;
        for (int w = wA; w < wE; ++w) {
            float fw = (float)w;
            float u = fmaf(fw, -si, iy0);          // row coord
            float v = fmaf(fw,  co, ix0);          // col coord
            float fu = floorf(u), fv = floorf(v);
            float wu = u - fu, wv = v - fv;
            int iu = (int)fu, iv = (int)fv;
            iu = min(max(iu, -2), 128);            // v_med3
            iv = min(max(iv, -2), 128);
            const float* q = base2 + iu * STR + iv;
            float q0 = q[0],   q1 = q[1];          // ds_read2
            float q2 = q[STR], q3 = q[STR + 1];    // ds_read2 (same addr reg)
            float r0 = fmaf(wv, q1 - q0, q0);
            float r1 = fmaf(wv, q3 - q2, q2);
            acc += fmaf(wu, r1 - r0, r0);
        }
        sigl[p] = acc;
    }
    __syncthreads();

    // --- Wavelet chain on sigl (6 rows of 128). Scratch overlays img. ---
    float* cur = img;            // 6*64
    float* f1  = img + 384;      // 6*64
    float* p1  = img + 768;      // 6*32
    float* u1  = img + 960;      // 6*64
    float g0 = wf0[0], g1 = wf0[1], g2 = wf0[2];

    for (int p = t; p < 768; p += 256) {           // c0 = conv3(sig)
        int k = p >> 7, h = p & 127;
        const float* s = sigl + k * 128;
        float sm1 = (h > 0)   ? s[h - 1] : 0.f;
        float sp1 = (h < 127) ? s[h + 1] : 0.f;
        float c0 = sm1 * g0 + s[h] * g1 + sp1 * g2;
        ws[COEF_OFF + (((b * 6 + k) * 64 + c) * 2 + 0) * 128 + h] = c0;
    }
    for (int q = t; q < 384; q += 256) {           // cur = avgpool(sig)
        int k = q >> 6, l = q & 63;
        cur[q] = (sigl[k * 128 + 2 * l] + sigl[k * 128 + 2 * l + 1]) * 0.5f;
    }
    __syncthreads();

    float w10 = wf1[0], w11 = wf1[1], w12 = wf1[2], w13 = wf1[3], w14 = wf1[4];
    for (int q = t; q < 384; q += 256) {           // f1 = conv5(cur)
        int k = q >> 6, l = q & 63;
        const float* cu = cur + k * 64;
        float a = cu[l] * w12;
        a += (l >= 2)  ? cu[l - 2] * w10 : 0.f;
        a += (l >= 1)  ? cu[l - 1] * w11 : 0.f;
        a += (l <= 62) ? cu[l + 1] * w13 : 0.f;
        a += (l <= 61) ? cu[l + 2] * w14 : 0.f;
        f1[q] = a;
    }
    __syncthreads();

    for (int q = t; q < 192; q += 256) {           // p1 = avgpool(f1)
        int k = q >> 5, m = q & 31;
        p1[q] = (f1[k * 64 + 2 * m] + f1[k * 64 + 2 * m + 1]) * 0.5f;
    }
    __syncthreads();

    for (int q = t; q < 384; q += 256) {           // u1 = interp(p1: 32->64)
        int k = q >> 6, l = q & 63;
        float real = fminf(fmaxf(0.5f * (float)l - 0.25f, 0.f), 31.f);
        int i0 = (int)real;
        int i1 = min(i0 + 1, 31);
        float wv = real - (float)i0;
        u1[q] = p1[k * 32 + i0] * (1.f - wv) + p1[k * 32 + i1] * wv;
    }
    __syncthreads();

    for (int p = t; p < 768; p += 256) {           // c1 = interp(u1: 64->128)
        int k = p >> 7, h = p & 127;
        float real = fminf(fmaxf(0.5f * (float)h - 0.25f, 0.f), 63.f);
        int i0 = (int)real;
        int i1 = min(i0 + 1, 63);
        float wv = real - (float)i0;
        float c1 = u1[k * 64 + i0] * (1.f - wv) + u1[k * 64 + i1] * wv;
        ws[COEF_OFF + (((b * 6 + k) * 64 + c) * 2 + 1) * 128 + h] = c1;
    }
}

// ---------------------------------------------------------------------------
// Kernel 3: fusion GEMM (hoisted before the k->W interp) + BN affine +
// k(6)->w(128) align_corners=True interp + ReLU + store. S never hits HBM.
// Block = (b, o-half, h2-tile of 8). Grid 8*2*16 = 256 blocks, 41 KB LDS.
// LDS access: M reads = 8 consecutive addrs broadcast (free); W padded to
// stride 129 -> 8 distinct banks broadcast (free).
// ---------------------------------------------------------------------------
__global__ __launch_bounds__(256) void k_fuseout(const float* __restrict__ fuse_w,
                                                 const float* __restrict__ fuse_b,
                                                 const float* __restrict__ bn_gamma,
                                                 const float* __restrict__ bn_beta,
                                                 const float* __restrict__ bn_mean,
                                                 const float* __restrict__ bn_var,
                                                 const float* __restrict__ ws,
                                                 float* __restrict__ out) {
    int blk = blockIdx.x;
    int b = blk >> 5, oh = (blk >> 4) & 1, j = blk & 15;   // h2 in [8j, 8j+8)
    int t = threadIdx.x;
    __shared__ float M_l[6 * 128 * 8];   // [k][c2][h2'] 24 KB
    __shared__ float W_l[32 * 129];      // padded stride 129, 16.5 KB
    __shared__ float S_l[32 * 8 * 6];    // [o'][h2'][k] 6 KB

    // stage M with the torch .view permutation undone:
    // c2 = 2c + (hp>=64), h2 = 2*(hp&63) + s;  hp = half*64 + 4j + x4
    for (int i = t; i < 6144; i += 256) {
        int x4 = i & 3, half = (i >> 2) & 1, s = (i >> 3) & 1;
        int cc = (i >> 4) & 63, k = i >> 10;
        int hp = half * 64 + 4 * j + x4;
        int c2 = 2 * cc + half;
        int h2p = 2 * x4 + s;
        M_l[(k * 128 + c2) * 8 + h2p] =
            ws[COEF_OFF + (((b * 6 + k) * 64 + cc) * 2 + s) * 128 + hp];
    }
    for (int i = t; i < 4096; i += 256) {
        int op = i >> 7, c2 = i & 127;
        W_l[op * 129 + c2] = fuse_w[(oh * 32 + op) * 128 + c2];
    }
    __syncthreads();

    // GEMM: thread = (o' = t>>3, h2' = t&7); acc[k] over 128 c2
    {
        int op = t >> 3, h2p = t & 7;
        float acc[6] = {0.f, 0.f, 0.f, 0.f, 0.f, 0.f};
        const float* wrow = W_l + op * 129;
        #pragma unroll 4
        for (int c2 = 0; c2 < 128; ++c2) {
            float wv = wrow[c2];
            const float* m = M_l + c2 * 8 + h2p;
            #pragma unroll
            for (int k = 0; k < 6; ++k)
                acc[k] = fmaf(wv, m[k * 1024], acc[k]);
        }
        int o = oh * 32 + op;
        float scale = bn_gamma[o] * rsqrtf(bn_var[o] + 1e-5f);
        float shift = (fuse_b[o] - bn_mean[o]) * scale + bn_beta[o];
        float* srow = S_l + (op * 8 + h2p) * 6;
        #pragma unroll
        for (int k = 0; k < 6; ++k)
            srow[k] = fmaf(acc[k], scale, shift);
    }
    __syncthreads();

    // epilogue: k->w interp + relu + store. 32*8*128 outs, 128 per thread.
    for (int it = 0; it < 128; ++it) {
        int flat = it * 256 + t;
        int w = flat & 127, row = flat >> 7;       // row = o'*8 + h2'
        float pos = (float)w * (5.0f / 127.0f);
        int i0 = min((int)pos, 5);
        int i1 = min(i0 + 1, 5);
        float tt = pos - (float)i0;
        const float* srow = S_l + row * 6;
        float val = srow[i0] * (1.f - tt) + srow[i1] * tt;
        int o = oh * 32 + (row >> 3);
        int h2 = 8 * j + (row & 7);
        out[(((b * 64 + o) * 128) + h2) * 128 + w] = fmaxf(val, 0.f);
    }
}

// ---------------------------------------------------------------------------
extern "C" void kernel_launch(void* const* d_in, const int* in_sizes, int n_in,
                              void* d_out, int out_size, void* d_ws, size_t ws_size,
                              hipStream_t stream) {
    const float* x        = (const float*)d_in[0];
    const float* lin1_w   = (const float*)d_in[1];
    const float* lin1_b   = (const float*)d_in[2];
    const float* lin2_w   = (const float*)d_in[3];
    const float* lin2_b   = (const float*)d_in[4];
    const float* wf0      = (const float*)d_in[5];
    const float* wf1      = (const float*)d_in[6];
    const float* fuse_w   = (const float*)d_in[7];
    const float* fuse_b   = (const float*)d_in[8];
    const float* bn_gamma = (const float*)d_in[9];
    const float* bn_beta  = (const float*)d_in[10];
    const float* bn_mean  = (const float*)d_in[11];
    const float* bn_var   = (const float*)d_in[12];
    float* ws  = (float*)d_ws;        // needs 3.18 MB
    float* out = (float*)d_out;

    hipLaunchKernelGGL(k_pool,    dim3(BB * CC), dim3(256), 0, stream, x, ws);
    hipLaunchKernelGGL(k_radon,   dim3(BB * CC), dim3(256), 0, stream,
                       x, lin1_w, lin1_b, lin2_w, lin2_b, wf0, wf1, ws);
    hipLaunchKernelGGL(k_fuseout, dim3(256),     dim3(256), 0, stream,
                       fuse_w, fuse_b, bn_gamma, bn_beta, bn_mean, bn_var,
                       ws, out);
}

// Round 5
// 174.536 us; speedup vs baseline: 1.2087x; 1.0387x over previous
//
#include <hip/hip_runtime.h>
#include <math.h>

// Problem constants
#define BB 8
#define CC 64
#define HH 128
#define WW 128
#define KK 6

// Workspace layout (float offsets). Total 794,688 floats = 3.18 MB.
#define FEAT_OFF 0                      // [B][1024]
#define COEF_OFF 8192                   // [N=48][C=64][S=2][H=128] = 786432

// Radon LDS geometry: rows/cols -2..129 (2-px zero border), stride 133.
// 133 mod 32 = 5 -> inner-loop lane bank drift = 5co+si: no resonance at any
// of the 6 base angles (0:5, 36:4.6, 72:2.5, 108:-0.6, 144:-3.5, 180:-5).
#define STR  133
#define NROW 132
#define IMG_SZ (NROW * STR)            // 17556 floats = 70.2 KB

// ---------------------------------------------------------------------------
// Kernel 1: adaptive avg-pool 4x4 -> feat[b, c*16 + i*4 + j]
// ---------------------------------------------------------------------------
__global__ __launch_bounds__(256) void k_pool(const float* __restrict__ x,
                                              float* __restrict__ ws) {
    int bc = blockIdx.x;               // b*64 + c
    int b = bc >> 6, c = bc & 63;
    int t = threadIdx.x;
    __shared__ float pool_l[16];
    if (t < 16) pool_l[t] = 0.f;
    __syncthreads();
    const float4* img4 = (const float4*)(x + (size_t)bc * 16384);
    float acc[4] = {0.f, 0.f, 0.f, 0.f};
    int cb = (t & 31) >> 3;            // W-block (32 float4 per row, 8 per block)
    #pragma unroll
    for (int r = 0; r < 16; ++r) {
        float4 v = img4[r * 256 + t];
        acc[r >> 2] += (v.x + v.y) + (v.z + v.w);
    }
    #pragma unroll
    for (int rb = 0; rb < 4; ++rb)
        atomicAdd(&pool_l[rb * 4 + cb], acc[rb]);
    __syncthreads();
    if (t < 16)
        ws[FEAT_OFF + b * 1024 + c * 16 + t] = pool_l[t] * (1.0f / 1024.0f);
}

// ---------------------------------------------------------------------------
// Kernel 2: fused MLP (angles) + Radon + Wavelet. One block per (b,c),
// 256 threads, ~78 KB LDS -> 2 blocks/CU.
// Radon inner loop: per-lane exact [wA,wB] (slab + serial verify), NO clamps
// in the body -- the 2-px zero border guarantees all reachable taps are
// in-bounds and out-of-image taps read zeros (== padding_mode='zeros').
// Address = (int)fmaf(floor(row),133,floor(col)) -- exact, no integer mul.
// ---------------------------------------------------------------------------
__global__ __launch_bounds__(256) void k_radon(const float* __restrict__ x,
                                               const float* __restrict__ lin1_w,
                                               const float* __restrict__ lin1_b,
                                               const float* __restrict__ lin2_w,
                                               const float* __restrict__ lin2_b,
                                               const float* __restrict__ wf0,
                                               const float* __restrict__ wf1,
                                               float* __restrict__ ws) {
    int bc = blockIdx.x;
    int b = bc >> 6, c = bc & 63;
    int t = threadIdx.x;
    __shared__ float img[IMG_SZ];      // 70.2 KB
    __shared__ float sigl[768];        // [k][h]
    __shared__ float feat_l[8 * 132];  // padded stride 132 -> bank-clean MLP
    __shared__ float h_l[32];
    __shared__ float ang_l[6], ang_s[6];
    __shared__ float co_l[6], si_l[6];

    // --- zero border cells (no overlap with interior -> no race) ---
    for (int i = t; i < 2 * STR; i += 256) {       // rows -2,-1 and 128,129
        img[i] = 0.f;
        img[130 * STR + i] = 0.f;
    }
    if (t < 128) {                                  // cols -2,-1,128,129 + pad
        float* r = img + (t + 2) * STR;
        r[0] = 0.f; r[1] = 0.f; r[130] = 0.f; r[131] = 0.f; r[132] = 0.f;
    }
    // --- stage interior: img row y -> lds row y+2, col x+2 ---
    const float4* src4 = (const float4*)(x + (size_t)bc * 16384);
    for (int i = t; i < 4096; i += 256) {
        float4 v = src4[i];
        float* d = img + ((i >> 5) + 2) * STR + ((i & 31) << 2) + 2;
        d[0] = v.x; d[1] = v.y; d[2] = v.z; d[3] = v.w;
    }
    // --- inline MLP: feat -> angles ---
    const float* feat = ws + FEAT_OFF + b * 1024;
    for (int i = t; i < 1024; i += 256)
        feat_l[(i >> 7) * 132 + (i & 127)] = feat[i];
    __syncthreads();
    {
        int m = t >> 3, part = t & 7;
        const float4* wrow = (const float4*)(lin1_w + m * 1024 + part * 128);
        const float4* frow = (const float4*)(feat_l + part * 132);
        float acc = 0.f;
        #pragma unroll 8
        for (int i = 0; i < 32; ++i) {
            float4 wv = wrow[i], fv = frow[i];
            acc = fmaf(wv.x, fv.x, acc); acc = fmaf(wv.y, fv.y, acc);
            acc = fmaf(wv.z, fv.z, acc); acc = fmaf(wv.w, fv.w, acc);
        }
        acc += __shfl_xor(acc, 1);
        acc += __shfl_xor(acc, 2);
        acc += __shfl_xor(acc, 4);
        if (part == 0) h_l[m] = fmaxf(acc + lin1_b[m], 0.f);
    }
    __syncthreads();
    if (t < 6) {
        float a = lin2_b[t];
        #pragma unroll
        for (int i = 0; i < 32; ++i) a = fmaf(h_l[i], lin2_w[t * 32 + i], a);
        a = 36.0f * (float)t + a * 30.0f;          // base = linspace(0,180,6)
        ang_l[t] = fminf(fmaxf(a, 0.f), 180.f);
    }
    __syncthreads();
    if (t == 0) {
        float v[6];
        #pragma unroll
        for (int i = 0; i < 6; ++i) v[i] = ang_l[i];
        for (int i = 1; i < 6; ++i) {              // insertion sort
            float key = v[i]; int j = i - 1;
            while (j >= 0 && v[j] > key) { v[j + 1] = v[j]; --j; }
            v[j + 1] = key;
        }
        #pragma unroll
        for (int i = 0; i < 6; ++i) ang_s[i] = v[i];
    }
    __syncthreads();
    if (t < 6) {
        float th = ang_s[t] * (3.14159265358979323846f / 180.0f);
        co_l[t] = cosf(th);
        si_l[t] = sinf(th);
    }
    __syncthreads();

    const float* base2 = img + 2 * STR + 2;  // (r,c) -> base2[r*STR+c], r,c in [-2,129]

    // --- Radon: 768 (k,h) lines, 3 per thread, k wave-uniform per pass ---
    for (int p = t; p < 768; p += 256) {
        int k = p >> 7, h = p & 127;
        float co = co_l[k], si = si_l[k];
        float yc = fmaf((float)h, 2.0f / 127.0f, -1.0f);
        float ix0 = (fmaf(yc, si, -co) + 1.0f) * 63.5f;  // col; d/dw = +co
        float iy0 = (fmaf(yc, co,  si) + 1.0f) * 63.5f;  // row; d/dw = -si

        // slab estimate of {w : ix,iy in [-1,128]}  (exactness not required)
        float ic = 1.0f / co, is = 1.0f / (-si);
        float a1 = (-1.0f - ix0) * ic, a2 = (128.0f - ix0) * ic;
        float b1 = (-1.0f - iy0) * is, b2 = (128.0f - iy0) * is;
        float wlo = fmaxf(fminf(a1, a2), fminf(b1, b2));
        float whi = fminf(fmaxf(a1, a2), fmaxf(b1, b2));
        int wA = max((int)ceilf(fmaxf(fminf(wlo, 200.f), -200.f)), 0);
        int wB = min((int)floorf(fmaxf(fminf(whi, 200.f), -200.f)), 127);
        // serial verify (exact predicate; typically 0-1 steps). Guarantees
        // every sampled w has ix,iy in [-1,128] -> taps within padded LDS.
        while (wA <= wB) {
            float cx = fmaf((float)wA, co, ix0), ry = fmaf((float)wA, -si, iy0);
            if (cx >= -1.f && cx <= 128.f && ry >= -1.f && ry <= 128.f) break;
            ++wA;
        }
        while (wB >= wA) {
            float cx = fmaf((float)wB, co, ix0), ry = fmaf((float)wB, -si, iy0);
            if (cx >= -1.f && cx <= 128.f && ry >= -1.f && ry <= 128.f) break;
            --wB;
        }

        float rr = fmaf((float)wA, -si, iy0);      // row coord
        float cc = fmaf((float)wA,  co, ix0);      // col coord
        float acc = 0.f;
        for (int i = wB - wA; i >= 0; --i) {
            float fr = floorf(rr), fc = floorf(cc);
            float wr = rr - fr,   wc = cc - fc;
            int idx = (int)fmaf(fr, 133.f, fc);    // exact int in float
            const float* q = base2 + idx;
            float q0 = q[0],   q1 = q[1];          // ds_read2
            float q2 = q[STR], q3 = q[STR + 1];    // ds_read2
            rr -= si;
            cc += co;
            float t0 = fmaf(wc, q1 - q0, q0);
            float t1 = fmaf(wc, q3 - q2, q2);
            acc += fmaf(wr, t1 - t0, t0);
        }
        sigl[p] = acc;
    }
    __syncthreads();

    // --- Wavelet chain on sigl (6 rows of 128). Scratch overlays img. ---
    float* cur = img;            // 6*64
    float* f1  = img + 384;      // 6*64
    float* p1  = img + 768;      // 6*32
    float* u1  = img + 960;      // 6*64
    float g0 = wf0[0], g1 = wf0[1], g2 = wf0[2];

    for (int p = t; p < 768; p += 256) {           // c0 = conv3(sig)
        int k = p >> 7, h = p & 127;
        const float* s = sigl + k * 128;
        float sm1 = (h > 0)   ? s[h - 1] : 0.f;
        float sp1 = (h < 127) ? s[h + 1] : 0.f;
        float c0 = sm1 * g0 + s[h] * g1 + sp1 * g2;
        ws[COEF_OFF + (((b * 6 + k) * 64 + c) * 2 + 0) * 128 + h] = c0;
    }
    for (int q = t; q < 384; q += 256) {           // cur = avgpool(sig)
        int k = q >> 6, l = q & 63;
        cur[q] = (sigl[k * 128 + 2 * l] + sigl[k * 128 + 2 * l + 1]) * 0.5f;
    }
    __syncthreads();

    float w10 = wf1[0], w11 = wf1[1], w12 = wf1[2], w13 = wf1[3], w14 = wf1[4];
    for (int q = t; q < 384; q += 256) {           // f1 = conv5(cur)
        int k = q >> 6, l = q & 63;
        const float* cu = cur + k * 64;
        float a = cu[l] * w12;
        a += (l >= 2)  ? cu[l - 2] * w10 : 0.f;
        a += (l >= 1)  ? cu[l - 1] * w11 : 0.f;
        a += (l <= 62) ? cu[l + 1] * w13 : 0.f;
        a += (l <= 61) ? cu[l + 2] * w14 : 0.f;
        f1[q] = a;
    }
    __syncthreads();

    for (int q = t; q < 192; q += 256) {           // p1 = avgpool(f1)
        int k = q >> 5, m = q & 31;
        p1[q] = (f1[k * 64 + 2 * m] + f1[k * 64 + 2 * m + 1]) * 0.5f;
    }
    __syncthreads();

    for (int q = t; q < 384; q += 256) {           // u1 = interp(p1: 32->64)
        int k = q >> 6, l = q & 63;
        float real = fminf(fmaxf(0.5f * (float)l - 0.25f, 0.f), 31.f);
        int i0 = (int)real;
        int i1 = min(i0 + 1, 31);
        float wv = real - (float)i0;
        u1[q] = p1[k * 32 + i0] * (1.f - wv) + p1[k * 32 + i1] * wv;
    }
    __syncthreads();

    for (int p = t; p < 768; p += 256) {           // c1 = interp(u1: 64->128)
        int k = p >> 7, h = p & 127;
        float real = fminf(fmaxf(0.5f * (float)h - 0.25f, 0.f), 63.f);
        int i0 = (int)real;
        int i1 = min(i0 + 1, 63);
        float wv = real - (float)i0;
        float c1 = u1[k * 64 + i0] * (1.f - wv) + u1[k * 64 + i1] * wv;
        ws[COEF_OFF + (((b * 6 + k) * 64 + c) * 2 + 1) * 128 + h] = c1;
    }
}

// ---------------------------------------------------------------------------
// Kernel 3: fusion GEMM (hoisted before the k->W interp) + BN affine +
// k(6)->w(128) align_corners=True interp + ReLU + store. S never hits HBM.
// Block = (b, o-half, h2-tile of 8). Grid 256 blocks, 47 KB LDS.
// ---------------------------------------------------------------------------
__global__ __launch_bounds__(256) void k_fuseout(const float* __restrict__ fuse_w,
                                                 const float* __restrict__ fuse_b,
                                                 const float* __restrict__ bn_gamma,
                                                 const float* __restrict__ bn_beta,
                                                 const float* __restrict__ bn_mean,
                                                 const float* __restrict__ bn_var,
                                                 const float* __restrict__ ws,
                                                 float* __restrict__ out) {
    int blk = blockIdx.x;
    int b = blk >> 5, oh = (blk >> 4) & 1, j = blk & 15;   // h2 in [8j, 8j+8)
    int t = threadIdx.x;
    __shared__ float M_l[6 * 128 * 8];   // [k][c2][h2'] 24 KB
    __shared__ float W_l[32 * 129];      // padded stride 129, 16.5 KB
    __shared__ float S_l[32 * 8 * 6];    // [o'][h2'][k] 6 KB

    // stage M with the torch .view permutation undone:
    // c2 = 2c + (hp>=64), h2 = 2*(hp&63) + s;  hp = half*64 + 4j + x4
    for (int i = t; i < 6144; i += 256) {
        int x4 = i & 3, half = (i >> 2) & 1, s = (i >> 3) & 1;
        int cc = (i >> 4) & 63, k = i >> 10;
        int hp = half * 64 + 4 * j + x4;
        int c2 = 2 * cc + half;
        int h2p = 2 * x4 + s;
        M_l[(k * 128 + c2) * 8 + h2p] =
            ws[COEF_OFF + (((b * 6 + k) * 64 + cc) * 2 + s) * 128 + hp];
    }
    for (int i = t; i < 4096; i += 256) {
        int op = i >> 7, c2 = i & 127;
        W_l[op * 129 + c2] = fuse_w[(oh * 32 + op) * 128 + c2];
    }
    __syncthreads();

    // GEMM: thread = (o' = t>>3, h2' = t&7); acc[k] over 128 c2
    {
        int op = t >> 3, h2p = t & 7;
        float acc[6] = {0.f, 0.f, 0.f, 0.f, 0.f, 0.f};
        const float* wrow = W_l + op * 129;
        #pragma unroll 4
        for (int c2 = 0; c2 < 128; ++c2) {
            float wv = wrow[c2];
            const float* m = M_l + c2 * 8 + h2p;
            #pragma unroll
            for (int k = 0; k < 6; ++k)
                acc[k] = fmaf(wv, m[k * 1024], acc[k]);
        }
        int o = oh * 32 + op;
        float scale = bn_gamma[o] * rsqrtf(bn_var[o] + 1e-5f);
        float shift = (fuse_b[o] - bn_mean[o]) * scale + bn_beta[o];
        float* srow = S_l + (op * 8 + h2p) * 6;
        #pragma unroll
        for (int k = 0; k < 6; ++k)
            srow[k] = fmaf(acc[k], scale, shift);
    }
    __syncthreads();

    // epilogue: k->w interp + relu + store. 32*8*128 outs, 128 per thread.
    for (int it = 0; it < 128; ++it) {
        int flat = it * 256 + t;
        int w = flat & 127, row = flat >> 7;       // row = o'*8 + h2'
        float pos = (float)w * (5.0f / 127.0f);
        int i0 = min((int)pos, 5);
        int i1 = min(i0 + 1, 5);
        float tt = pos - (float)i0;
        const float* srow = S_l + row * 6;
        float val = srow[i0] * (1.f - tt) + srow[i1] * tt;
        int o = oh * 32 + (row >> 3);
        int h2 = 8 * j + (row & 7);
        out[(((b * 64 + o) * 128) + h2) * 128 + w] = fmaxf(val, 0.f);
    }
}

// ---------------------------------------------------------------------------
extern "C" void kernel_launch(void* const* d_in, const int* in_sizes, int n_in,
                              void* d_out, int out_size, void* d_ws, size_t ws_size,
                              hipStream_t stream) {
    const float* x        = (const float*)d_in[0];
    const float* lin1_w   = (const float*)d_in[1];
    const float* lin1_b   = (const float*)d_in[2];
    const float* lin2_w   = (const float*)d_in[3];
    const float* lin2_b   = (const float*)d_in[4];
    const float* wf0      = (const float*)d_in[5];
    const float* wf1      = (const float*)d_in[6];
    const float* fuse_w   = (const float*)d_in[7];
    const float* fuse_b   = (const float*)d_in[8];
    const float* bn_gamma = (const float*)d_in[9];
    const float* bn_beta  = (const float*)d_in[10];
    const float* bn_mean  = (const float*)d_in[11];
    const float* bn_var   = (const float*)d_in[12];
    float* ws  = (float*)d_ws;        // needs 3.18 MB
    float* out = (float*)d_out;

    hipLaunchKernelGGL(k_pool,    dim3(BB * CC), dim3(256), 0, stream, x, ws);
    hipLaunchKernelGGL(k_radon,   dim3(BB * CC), dim3(256), 0, stream,
                       x, lin1_w, lin1_b, lin2_w, lin2_b, wf0, wf1, ws);
    hipLaunchKernelGGL(k_fuseout, dim3(256),     dim3(256), 0, stream,
                       fuse_w, fuse_b, bn_gamma, bn_beta, bn_mean, bn_var,
                       ws, out);
}

// Round 6
// 170.617 us; speedup vs baseline: 1.2365x; 1.0230x over previous
//
#include <hip/hip_runtime.h>
#include <math.h>

// Problem constants
#define BB 8
#define CC 64
#define HH 128
#define WW 128
#define KK 6

// Workspace layout (float offsets). Total 794,688 floats = 3.18 MB.
#define FEAT_OFF 0                      // [B][1024]
#define COEF_OFF 8192                   // [N=48][C=64][S=2][H=128] = 786432

// Radon LDS geometry: rows/cols -2..129 (2-px zero border), stride 133.
// Lane bank drift (consecutive h) = (133*co + si) mod 32 = 5co+si: worst case
// over base angles is ~0.6 at 108deg => ~2-way (free per m136).
#define STR  133
#define NROW 132
#define IMG_SZ (NROW * STR)            // 17556 floats = 70.2 KB

// ---------------------------------------------------------------------------
// Kernel 1: adaptive avg-pool 4x4 -> feat[b, c*16 + i*4 + j]
// ---------------------------------------------------------------------------
__global__ __launch_bounds__(256) void k_pool(const float* __restrict__ x,
                                              float* __restrict__ ws) {
    int bc = blockIdx.x;               // b*64 + c
    int b = bc >> 6, c = bc & 63;
    int t = threadIdx.x;
    __shared__ float pool_l[16];
    if (t < 16) pool_l[t] = 0.f;
    __syncthreads();
    const float4* img4 = (const float4*)(x + (size_t)bc * 16384);
    float acc[4] = {0.f, 0.f, 0.f, 0.f};
    int cb = (t & 31) >> 3;            // W-block (32 float4 per row, 8 per block)
    #pragma unroll
    for (int r = 0; r < 16; ++r) {
        float4 v = img4[r * 256 + t];
        acc[r >> 2] += (v.x + v.y) + (v.z + v.w);
    }
    #pragma unroll
    for (int rb = 0; rb < 4; ++rb)
        atomicAdd(&pool_l[rb * 4 + cb], acc[rb]);
    __syncthreads();
    if (t < 16)
        ws[FEAT_OFF + b * 1024 + c * 16 + t] = pool_l[t] * (1.0f / 1024.0f);
}

// one bilinear sample from the padded LDS image
#define SAMPLE(RR, CC, ACC) do {                                   \
    float fr_ = floorf(RR), fc_ = floorf(CC);                      \
    float wr_ = (RR) - fr_, wc_ = (CC) - fc_;                      \
    const float* q_ = base2 + (int)fmaf(fr_, 133.f, fc_);          \
    float q0_ = q_[0],   q1_ = q_[1];          /* ds_read2 */      \
    float q2_ = q_[STR], q3_ = q_[STR + 1];    /* ds_read2 */      \
    float t0_ = fmaf(wc_, q1_ - q0_, q0_);                         \
    float t1_ = fmaf(wc_, q3_ - q2_, q2_);                         \
    ACC += fmaf(wr_, t1_ - t0_, t0_);                              \
} while (0)

// ---------------------------------------------------------------------------
// Kernel 2: fused MLP (angles) + Radon + Wavelet. One block per (b,c),
// 256 threads, ~78 KB LDS -> 2 blocks/CU (2 waves/SIMD).
// Inner loop is 4-way unrolled with 4 independent (rr,cc,acc) chains so each
// wave keeps 8 ds_read2 in flight -- covers ~120cy LDS latency at only
// 2 waves/SIMD. Remainder: after m full iterations chain heads 0..2 sit
// exactly at samples 4m,4m+1,4m+2 (no fixup increments needed).
// Incremental coord drift <= 2.4e-4 over <=32 strided steps; the 2-px zero
// border absorbs floor() reaching -2 / col 129.
// ---------------------------------------------------------------------------
__global__ __launch_bounds__(256) void k_radon(const float* __restrict__ x,
                                               const float* __restrict__ lin1_w,
                                               const float* __restrict__ lin1_b,
                                               const float* __restrict__ lin2_w,
                                               const float* __restrict__ lin2_b,
                                               const float* __restrict__ wf0,
                                               const float* __restrict__ wf1,
                                               float* __restrict__ ws) {
    int bc = blockIdx.x;
    int b = bc >> 6, c = bc & 63;
    int t = threadIdx.x;
    __shared__ float img[IMG_SZ];      // 70.2 KB
    __shared__ float sigl[768];        // [k][h]
    __shared__ float feat_l[8 * 132];  // padded stride 132 -> bank-clean MLP
    __shared__ float h_l[32];
    __shared__ float ang_l[6], ang_s[6];
    __shared__ float co_l[6], si_l[6];

    // --- zero border cells (no overlap with interior -> no race) ---
    for (int i = t; i < 2 * STR; i += 256) {       // rows -2,-1 and 128,129
        img[i] = 0.f;
        img[130 * STR + i] = 0.f;
    }
    if (t < 128) {                                  // cols -2,-1,128,129 + pad
        float* r = img + (t + 2) * STR;
        r[0] = 0.f; r[1] = 0.f; r[130] = 0.f; r[131] = 0.f; r[132] = 0.f;
    }
    // --- stage interior: img row y -> lds row y+2, col x+2 ---
    const float4* src4 = (const float4*)(x + (size_t)bc * 16384);
    for (int i = t; i < 4096; i += 256) {
        float4 v = src4[i];
        float* d = img + ((i >> 5) + 2) * STR + ((i & 31) << 2) + 2;
        d[0] = v.x; d[1] = v.y; d[2] = v.z; d[3] = v.w;
    }
    // --- inline MLP: feat -> angles ---
    const float* feat = ws + FEAT_OFF + b * 1024;
    for (int i = t; i < 1024; i += 256)
        feat_l[(i >> 7) * 132 + (i & 127)] = feat[i];
    __syncthreads();
    {
        int m = t >> 3, part = t & 7;
        const float4* wrow = (const float4*)(lin1_w + m * 1024 + part * 128);
        const float4* frow = (const float4*)(feat_l + part * 132);
        float acc = 0.f;
        #pragma unroll 8
        for (int i = 0; i < 32; ++i) {
            float4 wv = wrow[i], fv = frow[i];
            acc = fmaf(wv.x, fv.x, acc); acc = fmaf(wv.y, fv.y, acc);
            acc = fmaf(wv.z, fv.z, acc); acc = fmaf(wv.w, fv.w, acc);
        }
        acc += __shfl_xor(acc, 1);
        acc += __shfl_xor(acc, 2);
        acc += __shfl_xor(acc, 4);
        if (part == 0) h_l[m] = fmaxf(acc + lin1_b[m], 0.f);
    }
    __syncthreads();
    if (t < 6) {
        float a = lin2_b[t];
        #pragma unroll
        for (int i = 0; i < 32; ++i) a = fmaf(h_l[i], lin2_w[t * 32 + i], a);
        a = 36.0f * (float)t + a * 30.0f;          // base = linspace(0,180,6)
        ang_l[t] = fminf(fmaxf(a, 0.f), 180.f);
    }
    __syncthreads();
    if (t == 0) {
        float v[6];
        #pragma unroll
        for (int i = 0; i < 6; ++i) v[i] = ang_l[i];
        for (int i = 1; i < 6; ++i) {              // insertion sort
            float key = v[i]; int j = i - 1;
            while (j >= 0 && v[j] > key) { v[j + 1] = v[j]; --j; }
            v[j + 1] = key;
        }
        #pragma unroll
        for (int i = 0; i < 6; ++i) ang_s[i] = v[i];
    }
    __syncthreads();
    if (t < 6) {
        float th = ang_s[t] * (3.14159265358979323846f / 180.0f);
        co_l[t] = cosf(th);
        si_l[t] = sinf(th);
    }
    __syncthreads();

    const float* base2 = img + 2 * STR + 2;  // (r,c) -> base2[r*STR+c], r,c in [-2,129]

    // --- Radon: 768 (k,h) lines, 3 per thread, k wave-uniform per pass ---
    for (int p = t; p < 768; p += 256) {
        int k = p >> 7, h = p & 127;
        float co = co_l[k], si = si_l[k];
        float yc = fmaf((float)h, 2.0f / 127.0f, -1.0f);
        float ix0 = (fmaf(yc, si, -co) + 1.0f) * 63.5f;  // col; d/dw = +co
        float iy0 = (fmaf(yc, co,  si) + 1.0f) * 63.5f;  // row; d/dw = -si

        // slab estimate of {w : ix,iy in [-1,128]}  (exactness not required)
        float ic = 1.0f / co, is = 1.0f / (-si);
        float a1 = (-1.0f - ix0) * ic, a2 = (128.0f - ix0) * ic;
        float b1 = (-1.0f - iy0) * is, b2 = (128.0f - iy0) * is;
        float wlo = fmaxf(fminf(a1, a2), fminf(b1, b2));
        float whi = fminf(fmaxf(a1, a2), fmaxf(b1, b2));
        int wA = max((int)ceilf(fmaxf(fminf(wlo, 200.f), -200.f)), 0);
        int wB = min((int)floorf(fmaxf(fminf(whi, 200.f), -200.f)), 127);
        // serial verify (exact predicate; typically 0-1 steps). Guarantees
        // every sampled w has ix,iy in [-1,128] -> taps within padded LDS.
        while (wA <= wB) {
            float cx = fmaf((float)wA, co, ix0), ry = fmaf((float)wA, -si, iy0);
            if (cx >= -1.f && cx <= 128.f && ry >= -1.f && ry <= 128.f) break;
            ++wA;
        }
        while (wB >= wA) {
            float cx = fmaf((float)wB, co, ix0), ry = fmaf((float)wB, -si, iy0);
            if (cx >= -1.f && cx <= 128.f && ry >= -1.f && ry <= 128.f) break;
            --wB;
        }

        int n = wB - wA + 1;
        float rr0 = fmaf((float)wA, -si, iy0);     // 4 independent chains
        float cc0 = fmaf((float)wA,  co, ix0);
        float rr1 = rr0 - si, cc1 = cc0 + co;
        float rr2 = rr1 - si, cc2 = cc1 + co;
        float rr3 = rr2 - si, cc3 = cc2 + co;
        float si4 = 4.0f * si, co4 = 4.0f * co;
        float a0 = 0.f, aa1 = 0.f, aa2 = 0.f, a3 = 0.f;
        int i = n;
        while (i >= 4) {
            SAMPLE(rr0, cc0, a0);
            SAMPLE(rr1, cc1, aa1);
            SAMPLE(rr2, cc2, aa2);
            SAMPLE(rr3, cc3, a3);
            rr0 -= si4; cc0 += co4;
            rr1 -= si4; cc1 += co4;
            rr2 -= si4; cc2 += co4;
            rr3 -= si4; cc3 += co4;
            i -= 4;
        }
        if (i > 0) SAMPLE(rr0, cc0, a0);   // chain heads already positioned
        if (i > 1) SAMPLE(rr1, cc1, aa1);
        if (i > 2) SAMPLE(rr2, cc2, aa2);
        sigl[p] = (a0 + aa1) + (aa2 + a3);
    }
    __syncthreads();

    // --- Wavelet chain on sigl (6 rows of 128). Scratch overlays img. ---
    float* cur = img;            // 6*64
    float* f1  = img + 384;      // 6*64
    float* p1  = img + 768;      // 6*32
    float* u1  = img + 960;      // 6*64
    float g0 = wf0[0], g1 = wf0[1], g2 = wf0[2];

    for (int p = t; p < 768; p += 256) {           // c0 = conv3(sig)
        int k = p >> 7, h = p & 127;
        const float* s = sigl + k * 128;
        float sm1 = (h > 0)   ? s[h - 1] : 0.f;
        float sp1 = (h < 127) ? s[h + 1] : 0.f;
        float c0 = sm1 * g0 + s[h] * g1 + sp1 * g2;
        ws[COEF_OFF + (((b * 6 + k) * 64 + c) * 2 + 0) * 128 + h] = c0;
    }
    for (int q = t; q < 384; q += 256) {           // cur = avgpool(sig)
        int k = q >> 6, l = q & 63;
        cur[q] = (sigl[k * 128 + 2 * l] + sigl[k * 128 + 2 * l + 1]) * 0.5f;
    }
    __syncthreads();

    float w10 = wf1[0], w11 = wf1[1], w12 = wf1[2], w13 = wf1[3], w14 = wf1[4];
    for (int q = t; q < 384; q += 256) {           // f1 = conv5(cur)
        int k = q >> 6, l = q & 63;
        const float* cu = cur + k * 64;
        float a = cu[l] * w12;
        a += (l >= 2)  ? cu[l - 2] * w10 : 0.f;
        a += (l >= 1)  ? cu[l - 1] * w11 : 0.f;
        a += (l <= 62) ? cu[l + 1] * w13 : 0.f;
        a += (l <= 61) ? cu[l + 2] * w14 : 0.f;
        f1[q] = a;
    }
    __syncthreads();

    for (int q = t; q < 192; q += 256) {           // p1 = avgpool(f1)
        int k = q >> 5, m = q & 31;
        p1[q] = (f1[k * 64 + 2 * m] + f1[k * 64 + 2 * m + 1]) * 0.5f;
    }
    __syncthreads();

    for (int q = t; q < 384; q += 256) {           // u1 = interp(p1: 32->64)
        int k = q >> 6, l = q & 63;
        float real = fminf(fmaxf(0.5f * (float)l - 0.25f, 0.f), 31.f);
        int i0 = (int)real;
        int i1 = min(i0 + 1, 31);
        float wv = real - (float)i0;
        u1[q] = p1[k * 32 + i0] * (1.f - wv) + p1[k * 32 + i1] * wv;
    }
    __syncthreads();

    for (int p = t; p < 768; p += 256) {           // c1 = interp(u1: 64->128)
        int k = p >> 7, h = p & 127;
        float real = fminf(fmaxf(0.5f * (float)h - 0.25f, 0.f), 63.f);
        int i0 = (int)real;
        int i1 = min(i0 + 1, 63);
        float wv = real - (float)i0;
        float c1 = u1[k * 64 + i0] * (1.f - wv) + u1[k * 64 + i1] * wv;
        ws[COEF_OFF + (((b * 6 + k) * 64 + c) * 2 + 1) * 128 + h] = c1;
    }
}

// ---------------------------------------------------------------------------
// Kernel 3: fusion GEMM (hoisted before the k->W interp) + BN affine +
// k(6)->w(128) align_corners=True interp + ReLU + store. S never hits HBM.
// Block = (b, o-half, h2-tile of 8). Grid 256 blocks, 47 KB LDS.
// ---------------------------------------------------------------------------
__global__ __launch_bounds__(256) void k_fuseout(const float* __restrict__ fuse_w,
                                                 const float* __restrict__ fuse_b,
                                                 const float* __restrict__ bn_gamma,
                                                 const float* __restrict__ bn_beta,
                                                 const float* __restrict__ bn_mean,
                                                 const float* __restrict__ bn_var,
                                                 const float* __restrict__ ws,
                                                 float* __restrict__ out) {
    int blk = blockIdx.x;
    int b = blk >> 5, oh = (blk >> 4) & 1, j = blk & 15;   // h2 in [8j, 8j+8)
    int t = threadIdx.x;
    __shared__ float M_l[6 * 128 * 8];   // [k][c2][h2'] 24 KB
    __shared__ float W_l[32 * 129];      // padded stride 129, 16.5 KB
    __shared__ float S_l[32 * 8 * 6];    // [o'][h2'][k] 6 KB

    // stage M with the torch .view permutation undone:
    // c2 = 2c + (hp>=64), h2 = 2*(hp&63) + s;  hp = half*64 + 4j + x4
    for (int i = t; i < 6144; i += 256) {
        int x4 = i & 3, half = (i >> 2) & 1, s = (i >> 3) & 1;
        int cc = (i >> 4) & 63, k = i >> 10;
        int hp = half * 64 + 4 * j + x4;
        int c2 = 2 * cc + half;
        int h2p = 2 * x4 + s;
        M_l[(k * 128 + c2) * 8 + h2p] =
            ws[COEF_OFF + (((b * 6 + k) * 64 + cc) * 2 + s) * 128 + hp];
    }
    for (int i = t; i < 4096; i += 256) {
        int op = i >> 7, c2 = i & 127;
        W_l[op * 129 + c2] = fuse_w[(oh * 32 + op) * 128 + c2];
    }
    __syncthreads();

    // GEMM: thread = (o' = t>>3, h2' = t&7); acc[k] over 128 c2
    {
        int op = t >> 3, h2p = t & 7;
        float acc[6] = {0.f, 0.f, 0.f, 0.f, 0.f, 0.f};
        const float* wrow = W_l + op * 129;
        #pragma unroll 4
        for (int c2 = 0; c2 < 128; ++c2) {
            float wv = wrow[c2];
            const float* m = M_l + c2 * 8 + h2p;
            #pragma unroll
            for (int k = 0; k < 6; ++k)
                acc[k] = fmaf(wv, m[k * 1024], acc[k]);
        }
        int o = oh * 32 + op;
        float scale = bn_gamma[o] * rsqrtf(bn_var[o] + 1e-5f);
        float shift = (fuse_b[o] - bn_mean[o]) * scale + bn_beta[o];
        float* srow = S_l + (op * 8 + h2p) * 6;
        #pragma unroll
        for (int k = 0; k < 6; ++k)
            srow[k] = fmaf(acc[k], scale, shift);
    }
    __syncthreads();

    // epilogue: k->w interp + relu + store. 32*8*128 outs, 128 per thread.
    for (int it = 0; it < 128; ++it) {
        int flat = it * 256 + t;
        int w = flat & 127, row = flat >> 7;       // row = o'*8 + h2'
        float pos = (float)w * (5.0f / 127.0f);
        int i0 = min((int)pos, 5);
        int i1 = min(i0 + 1, 5);
        float tt = pos - (float)i0;
        const float* srow = S_l + row * 6;
        float val = srow[i0] * (1.f - tt) + srow[i1] * tt;
        int o = oh * 32 + (row >> 3);
        int h2 = 8 * j + (row & 7);
        out[(((b * 64 + o) * 128) + h2) * 128 + w] = fmaxf(val, 0.f);
    }
}

// ---------------------------------------------------------------------------
extern "C" void kernel_launch(void* const* d_in, const int* in_sizes, int n_in,
                              void* d_out, int out_size, void* d_ws, size_t ws_size,
                              hipStream_t stream) {
    const float* x        = (const float*)d_in[0];
    const float* lin1_w   = (const float*)d_in[1];
    const float* lin1_b   = (const float*)d_in[2];
    const float* lin2_w   = (const float*)d_in[3];
    const float* lin2_b   = (const float*)d_in[4];
    const float* wf0      = (const float*)d_in[5];
    const float* wf1      = (const float*)d_in[6];
    const float* fuse_w   = (const float*)d_in[7];
    const float* fuse_b   = (const float*)d_in[8];
    const float* bn_gamma = (const float*)d_in[9];
    const float* bn_beta  = (const float*)d_in[10];
    const float* bn_mean  = (const float*)d_in[11];
    const float* bn_var   = (const float*)d_in[12];
    float* ws  = (float*)d_ws;        // needs 3.18 MB
    float* out = (float*)d_out;

    hipLaunchKernelGGL(k_pool,    dim3(BB * CC), dim3(256), 0, stream, x, ws);
    hipLaunchKernelGGL(k_radon,   dim3(BB * CC), dim3(256), 0, stream,
                       x, lin1_w, lin1_b, lin2_w, lin2_b, wf0, wf1, ws);
    hipLaunchKernelGGL(k_fuseout, dim3(256),     dim3(256), 0, stream,
                       fuse_w, fuse_b, bn_gamma, bn_beta, bn_mean, bn_var,
                       ws, out);
}

// Round 7
// 169.322 us; speedup vs baseline: 1.2459x; 1.0076x over previous
//
#include <hip/hip_runtime.h>
#include <math.h>

// Problem constants
#define BB 8
#define CC 64
#define HH 128
#define WW 128
#define KK 6

// Workspace layout (float offsets). Total 794,688 floats = 3.18 MB.
#define FEAT_OFF 0                      // [B][1024]
#define COEF_OFF 8192                   // [N=48][C=64][S=2][H=128] = 786432

// Radon LDS geometry: rows/cols -2..129 (2-px zero border), stride 133.
// Lane bank drift (consecutive h) = (133*co + si) mod 32 = 5co+si: worst case
// over base angles is ~0.6 at 108deg => ~2-way (free per m136).
#define STR  133
#define NROW 132
#define IMG_SZ (NROW * STR)            // 17556 floats = 70.2 KB

// ---------------------------------------------------------------------------
// Kernel 1: adaptive avg-pool 4x4 -> feat[b, c*16 + i*4 + j]
// ---------------------------------------------------------------------------
__global__ __launch_bounds__(256) void k_pool(const float* __restrict__ x,
                                              float* __restrict__ ws) {
    int bc = blockIdx.x;               // b*64 + c
    int b = bc >> 6, c = bc & 63;
    int t = threadIdx.x;
    __shared__ float pool_l[16];
    if (t < 16) pool_l[t] = 0.f;
    __syncthreads();
    const float4* img4 = (const float4*)(x + (size_t)bc * 16384);
    float acc[4] = {0.f, 0.f, 0.f, 0.f};
    int cb = (t & 31) >> 3;            // W-block (32 float4 per row, 8 per block)
    #pragma unroll
    for (int r = 0; r < 16; ++r) {
        float4 v = img4[r * 256 + t];
        acc[r >> 2] += (v.x + v.y) + (v.z + v.w);
    }
    #pragma unroll
    for (int rb = 0; rb < 4; ++rb)
        atomicAdd(&pool_l[rb * 4 + cb], acc[rb]);
    __syncthreads();
    if (t < 16)
        ws[FEAT_OFF + b * 1024 + c * 16 + t] = pool_l[t] * (1.0f / 1024.0f);
}

// one bilinear sample from the padded LDS image
#define SAMPLE(RR, CC, ACC) do {                                   \
    float fr_ = floorf(RR), fc_ = floorf(CC);                      \
    float wr_ = (RR) - fr_, wc_ = (CC) - fc_;                      \
    const float* q_ = base2 + (int)fmaf(fr_, 133.f, fc_);          \
    float q0_ = q_[0],   q1_ = q_[1];          /* ds_read2 */      \
    float q2_ = q_[STR], q3_ = q_[STR + 1];    /* ds_read2 */      \
    float t0_ = fmaf(wc_, q1_ - q0_, q0_);                         \
    float t1_ = fmaf(wc_, q3_ - q2_, q2_);                         \
    ACC += fmaf(wr_, t1_ - t0_, t0_);                              \
} while (0)

// exact per-lane sample interval [wA,wB] (slab estimate + serial verify);
// guarantees every sampled w has ix,iy in [-1,128] -> taps in padded LDS.
__device__ __forceinline__ void line_bounds(float co, float si, float ix0,
                                            float iy0, int& wA, int& wB) {
    float ic = 1.0f / co, is = 1.0f / (-si);
    float a1 = (-1.0f - ix0) * ic, a2 = (128.0f - ix0) * ic;
    float b1 = (-1.0f - iy0) * is, b2 = (128.0f - iy0) * is;
    float wlo = fmaxf(fminf(a1, a2), fminf(b1, b2));
    float whi = fminf(fmaxf(a1, a2), fmaxf(b1, b2));
    wA = max((int)ceilf(fmaxf(fminf(wlo, 200.f), -200.f)), 0);
    wB = min((int)floorf(fmaxf(fminf(whi, 200.f), -200.f)), 127);
    while (wA <= wB) {
        float cx = fmaf((float)wA, co, ix0), ry = fmaf((float)wA, -si, iy0);
        if (cx >= -1.f && cx <= 128.f && ry >= -1.f && ry <= 128.f) break;
        ++wA;
    }
    while (wB >= wA) {
        float cx = fmaf((float)wB, co, ix0), ry = fmaf((float)wB, -si, iy0);
        if (cx >= -1.f && cx <= 128.f && ry >= -1.f && ry <= 128.f) break;
        --wB;
    }
}

// sum bilinear samples over w in [wA,wB]; 4 independent (rr,cc,acc) chains.
__device__ __forceinline__ float radon_line(const float* base2, float co,
                                            float si, float ix0, float iy0,
                                            int wA, int wB) {
    int n = wB - wA + 1;
    float rr0 = fmaf((float)wA, -si, iy0);
    float cc0 = fmaf((float)wA,  co, ix0);
    float rr1 = rr0 - si, cc1 = cc0 + co;
    float rr2 = rr1 - si, cc2 = cc1 + co;
    float rr3 = rr2 - si, cc3 = cc2 + co;
    float si4 = 4.0f * si, co4 = 4.0f * co;
    float a0 = 0.f, a1 = 0.f, a2 = 0.f, a3 = 0.f;
    int i = n;
    while (i >= 4) {
        SAMPLE(rr0, cc0, a0);
        SAMPLE(rr1, cc1, a1);
        SAMPLE(rr2, cc2, a2);
        SAMPLE(rr3, cc3, a3);
        rr0 -= si4; cc0 += co4;
        rr1 -= si4; cc1 += co4;
        rr2 -= si4; cc2 += co4;
        rr3 -= si4; cc3 += co4;
        i -= 4;
    }
    if (i > 0) SAMPLE(rr0, cc0, a0);   // chain heads already positioned
    if (i > 1) SAMPLE(rr1, cc1, a1);
    if (i > 2) SAMPLE(rr2, cc2, a2);
    return (a0 + a1) + (a2 + a3);
}

// ---------------------------------------------------------------------------
// Kernel 2: fused MLP (angles) + Radon + Wavelet. One block per (b,c),
// 512 threads (8 waves), ~78 KB LDS -> 2 blocks/CU = 16 waves/CU =
// 4 waves/SIMD (vs 2 at 256 threads) -- the LDS round-trip is now covered
// by TLP instead of relying on in-wave ILP the compiler wouldn't schedule.
// Work split: 768 lines = 512 full + 256 split-in-half (each half-line done
// by one lane of an even/odd pair, partials merged via shfl_xor) -- balanced.
// ---------------------------------------------------------------------------
__global__ __launch_bounds__(512, 4) void k_radon(const float* __restrict__ x,
                                                  const float* __restrict__ lin1_w,
                                                  const float* __restrict__ lin1_b,
                                                  const float* __restrict__ lin2_w,
                                                  const float* __restrict__ lin2_b,
                                                  const float* __restrict__ wf0,
                                                  const float* __restrict__ wf1,
                                                  float* __restrict__ ws) {
    int bc = blockIdx.x;
    int b = bc >> 6, c = bc & 63;
    int t = threadIdx.x;
    __shared__ float img[IMG_SZ];      // 70.2 KB
    __shared__ float sigl[768];        // [k][h]
    __shared__ float feat_l[8 * 132];  // padded stride 132 -> bank-clean MLP
    __shared__ float h_l[32];
    __shared__ float ang_l[6], ang_s[6];
    __shared__ float co_l[6], si_l[6];

    // --- zero border cells (no overlap with interior -> no race) ---
    for (int i = t; i < 2 * STR; i += 512) {       // rows -2,-1 and 128,129
        img[i] = 0.f;
        img[130 * STR + i] = 0.f;
    }
    if (t < 128) {                                  // cols -2,-1,128,129 + pad
        float* r = img + (t + 2) * STR;
        r[0] = 0.f; r[1] = 0.f; r[130] = 0.f; r[131] = 0.f; r[132] = 0.f;
    }
    // --- stage interior: img row y -> lds row y+2, col x+2 ---
    const float4* src4 = (const float4*)(x + (size_t)bc * 16384);
    for (int i = t; i < 4096; i += 512) {
        float4 v = src4[i];
        float* d = img + ((i >> 5) + 2) * STR + ((i & 31) << 2) + 2;
        d[0] = v.x; d[1] = v.y; d[2] = v.z; d[3] = v.w;
    }
    // --- inline MLP: feat -> angles (first 256 threads) ---
    const float* feat = ws + FEAT_OFF + b * 1024;
    for (int i = t; i < 1024; i += 512)
        feat_l[(i >> 7) * 132 + (i & 127)] = feat[i];
    __syncthreads();
    if (t < 256) {
        int m = t >> 3, part = t & 7;
        const float4* wrow = (const float4*)(lin1_w + m * 1024 + part * 128);
        const float4* frow = (const float4*)(feat_l + part * 132);
        float acc = 0.f;
        #pragma unroll 8
        for (int i = 0; i < 32; ++i) {
            float4 wv = wrow[i], fv = frow[i];
            acc = fmaf(wv.x, fv.x, acc); acc = fmaf(wv.y, fv.y, acc);
            acc = fmaf(wv.z, fv.z, acc); acc = fmaf(wv.w, fv.w, acc);
        }
        acc += __shfl_xor(acc, 1);
        acc += __shfl_xor(acc, 2);
        acc += __shfl_xor(acc, 4);
        if (part == 0) h_l[m] = fmaxf(acc + lin1_b[m], 0.f);
    }
    __syncthreads();
    if (t < 6) {
        float a = lin2_b[t];
        #pragma unroll
        for (int i = 0; i < 32; ++i) a = fmaf(h_l[i], lin2_w[t * 32 + i], a);
        a = 36.0f * (float)t + a * 30.0f;          // base = linspace(0,180,6)
        ang_l[t] = fminf(fmaxf(a, 0.f), 180.f);
    }
    __syncthreads();
    if (t == 0) {
        float v[6];
        #pragma unroll
        for (int i = 0; i < 6; ++i) v[i] = ang_l[i];
        for (int i = 1; i < 6; ++i) {              // insertion sort
            float key = v[i]; int j = i - 1;
            while (j >= 0 && v[j] > key) { v[j + 1] = v[j]; --j; }
            v[j + 1] = key;
        }
        #pragma unroll
        for (int i = 0; i < 6; ++i) ang_s[i] = v[i];
    }
    __syncthreads();
    if (t < 6) {
        float th = ang_s[t] * (3.14159265358979323846f / 180.0f);
        co_l[t] = cosf(th);
        si_l[t] = sinf(th);
    }
    __syncthreads();

    const float* base2 = img + 2 * STR + 2;  // (r,c) -> base2[r*STR+c], r,c in [-2,129]

    // --- Radon pass A: lines 0..511, one full line per thread ---
    {
        int p = t, k = p >> 7, h = p & 127;
        float co = co_l[k], si = si_l[k];
        float yc = fmaf((float)h, 2.0f / 127.0f, -1.0f);
        float ix0 = (fmaf(yc, si, -co) + 1.0f) * 63.5f;  // col; d/dw = +co
        float iy0 = (fmaf(yc, co,  si) + 1.0f) * 63.5f;  // row; d/dw = -si
        int wA, wB;
        line_bounds(co, si, ix0, iy0, wA, wB);
        sigl[p] = radon_line(base2, co, si, ix0, iy0, wA, wB);
    }
    // --- Radon pass B: lines 512..767, half-line per thread (even/odd) ---
    {
        int p = 512 + (t >> 1), k = p >> 7, h = p & 127;
        int half = t & 1;
        float co = co_l[k], si = si_l[k];
        float yc = fmaf((float)h, 2.0f / 127.0f, -1.0f);
        float ix0 = (fmaf(yc, si, -co) + 1.0f) * 63.5f;
        float iy0 = (fmaf(yc, co,  si) + 1.0f) * 63.5f;
        int wA, wB;
        line_bounds(co, si, ix0, iy0, wA, wB);
        int mid = wA + ((wB - wA + 1) >> 1);
        int sA = half ? mid : wA;
        int sB = half ? wB : (mid - 1);
        float a = radon_line(base2, co, si, ix0, iy0, sA, sB);
        a += __shfl_xor(a, 1);                     // merge the two halves
        if (half == 0) sigl[p] = a;
    }
    __syncthreads();

    // --- Wavelet chain on sigl (6 rows of 128). Scratch overlays img. ---
    float* cur = img;            // 6*64
    float* f1  = img + 384;      // 6*64
    float* p1  = img + 768;      // 6*32
    float* u1  = img + 960;      // 6*64
    float g0 = wf0[0], g1 = wf0[1], g2 = wf0[2];

    for (int p = t; p < 768; p += 512) {           // c0 = conv3(sig)
        int k = p >> 7, h = p & 127;
        const float* s = sigl + k * 128;
        float sm1 = (h > 0)   ? s[h - 1] : 0.f;
        float sp1 = (h < 127) ? s[h + 1] : 0.f;
        float c0 = sm1 * g0 + s[h] * g1 + sp1 * g2;
        ws[COEF_OFF + (((b * 6 + k) * 64 + c) * 2 + 0) * 128 + h] = c0;
    }
    for (int q = t; q < 384; q += 512) {           // cur = avgpool(sig)
        int k = q >> 6, l = q & 63;
        cur[q] = (sigl[k * 128 + 2 * l] + sigl[k * 128 + 2 * l + 1]) * 0.5f;
    }
    __syncthreads();

    float w10 = wf1[0], w11 = wf1[1], w12 = wf1[2], w13 = wf1[3], w14 = wf1[4];
    for (int q = t; q < 384; q += 512) {           // f1 = conv5(cur)
        int k = q >> 6, l = q & 63;
        const float* cu = cur + k * 64;
        float a = cu[l] * w12;
        a += (l >= 2)  ? cu[l - 2] * w10 : 0.f;
        a += (l >= 1)  ? cu[l - 1] * w11 : 0.f;
        a += (l <= 62) ? cu[l + 1] * w13 : 0.f;
        a += (l <= 61) ? cu[l + 2] * w14 : 0.f;
        f1[q] = a;
    }
    __syncthreads();

    for (int q = t; q < 192; q += 512) {           // p1 = avgpool(f1)
        int k = q >> 5, m = q & 31;
        p1[q] = (f1[k * 64 + 2 * m] + f1[k * 64 + 2 * m + 1]) * 0.5f;
    }
    __syncthreads();

    for (int q = t; q < 384; q += 512) {           // u1 = interp(p1: 32->64)
        int k = q >> 6, l = q & 63;
        float real = fminf(fmaxf(0.5f * (float)l - 0.25f, 0.f), 31.f);
        int i0 = (int)real;
        int i1 = min(i0 + 1, 31);
        float wv = real - (float)i0;
        u1[q] = p1[k * 32 + i0] * (1.f - wv) + p1[k * 32 + i1] * wv;
    }
    __syncthreads();

    for (int p = t; p < 768; p += 512) {           // c1 = interp(u1: 64->128)
        int k = p >> 7, h = p & 127;
        float real = fminf(fmaxf(0.5f * (float)h - 0.25f, 0.f), 63.f);
        int i0 = (int)real;
        int i1 = min(i0 + 1, 63);
        float wv = real - (float)i0;
        float c1 = u1[k * 64 + i0] * (1.f - wv) + u1[k * 64 + i1] * wv;
        ws[COEF_OFF + (((b * 6 + k) * 64 + c) * 2 + 1) * 128 + h] = c1;
    }
}

// ---------------------------------------------------------------------------
// Kernel 3: fusion GEMM (hoisted before the k->W interp) + BN affine +
// k(6)->w(128) align_corners=True interp + ReLU + store. S never hits HBM.
// Block = (b, o-half, h2-tile of 8). Grid 256 blocks, 47 KB LDS.
// ---------------------------------------------------------------------------
__global__ __launch_bounds__(256) void k_fuseout(const float* __restrict__ fuse_w,
                                                 const float* __restrict__ fuse_b,
                                                 const float* __restrict__ bn_gamma,
                                                 const float* __restrict__ bn_beta,
                                                 const float* __restrict__ bn_mean,
                                                 const float* __restrict__ bn_var,
                                                 const float* __restrict__ ws,
                                                 float* __restrict__ out) {
    int blk = blockIdx.x;
    int b = blk >> 5, oh = (blk >> 4) & 1, j = blk & 15;   // h2 in [8j, 8j+8)
    int t = threadIdx.x;
    __shared__ float M_l[6 * 128 * 8];   // [k][c2][h2'] 24 KB
    __shared__ float W_l[32 * 129];      // padded stride 129, 16.5 KB
    __shared__ float S_l[32 * 8 * 6];    // [o'][h2'][k] 6 KB

    // stage M with the torch .view permutation undone:
    // c2 = 2c + (hp>=64), h2 = 2*(hp&63) + s;  hp = half*64 + 4j + x4
    for (int i = t; i < 6144; i += 256) {
        int x4 = i & 3, half = (i >> 2) & 1, s = (i >> 3) & 1;
        int cc = (i >> 4) & 63, k = i >> 10;
        int hp = half * 64 + 4 * j + x4;
        int c2 = 2 * cc + half;
        int h2p = 2 * x4 + s;
        M_l[(k * 128 + c2) * 8 + h2p] =
            ws[COEF_OFF + (((b * 6 + k) * 64 + cc) * 2 + s) * 128 + hp];
    }
    for (int i = t; i < 4096; i += 256) {
        int op = i >> 7, c2 = i & 127;
        W_l[op * 129 + c2] = fuse_w[(oh * 32 + op) * 128 + c2];
    }
    __syncthreads();

    // GEMM: thread = (o' = t>>3, h2' = t&7); acc[k] over 128 c2
    {
        int op = t >> 3, h2p = t & 7;
        float acc[6] = {0.f, 0.f, 0.f, 0.f, 0.f, 0.f};
        const float* wrow = W_l + op * 129;
        #pragma unroll 4
        for (int c2 = 0; c2 < 128; ++c2) {
            float wv = wrow[c2];
            const float* m = M_l + c2 * 8 + h2p;
            #pragma unroll
            for (int k = 0; k < 6; ++k)
                acc[k] = fmaf(wv, m[k * 1024], acc[k]);
        }
        int o = oh * 32 + op;
        float scale = bn_gamma[o] * rsqrtf(bn_var[o] + 1e-5f);
        float shift = (fuse_b[o] - bn_mean[o]) * scale + bn_beta[o];
        float* srow = S_l + (op * 8 + h2p) * 6;
        #pragma unroll
        for (int k = 0; k < 6; ++k)
            srow[k] = fmaf(acc[k], scale, shift);
    }
    __syncthreads();

    // epilogue: k->w interp + relu + store. 32*8*128 outs, 128 per thread.
    for (int it = 0; it < 128; ++it) {
        int flat = it * 256 + t;
        int w = flat & 127, row = flat >> 7;       // row = o'*8 + h2'
        float pos = (float)w * (5.0f / 127.0f);
        int i0 = min((int)pos, 5);
        int i1 = min(i0 + 1, 5);
        float tt = pos - (float)i0;
        const float* srow = S_l + row * 6;
        float val = srow[i0] * (1.f - tt) + srow[i1] * tt;
        int o = oh * 32 + (row >> 3);
        int h2 = 8 * j + (row & 7);
        out[(((b * 64 + o) * 128) + h2) * 128 + w] = fmaxf(val, 0.f);
    }
}

// ---------------------------------------------------------------------------
extern "C" void kernel_launch(void* const* d_in, const int* in_sizes, int n_in,
                              void* d_out, int out_size, void* d_ws, size_t ws_size,
                              hipStream_t stream) {
    const float* x        = (const float*)d_in[0];
    const float* lin1_w   = (const float*)d_in[1];
    const float* lin1_b   = (const float*)d_in[2];
    const float* lin2_w   = (const float*)d_in[3];
    const float* lin2_b   = (const float*)d_in[4];
    const float* wf0      = (const float*)d_in[5];
    const float* wf1      = (const float*)d_in[6];
    const float* fuse_w   = (const float*)d_in[7];
    const float* fuse_b   = (const float*)d_in[8];
    const float* bn_gamma = (const float*)d_in[9];
    const float* bn_beta  = (const float*)d_in[10];
    const float* bn_mean  = (const float*)d_in[11];
    const float* bn_var   = (const float*)d_in[12];
    float* ws  = (float*)d_ws;        // needs 3.18 MB
    float* out = (float*)d_out;

    hipLaunchKernelGGL(k_pool,    dim3(BB * CC), dim3(256), 0, stream, x, ws);
    hipLaunchKernelGGL(k_radon,   dim3(BB * CC), dim3(512), 0, stream,
                       x, lin1_w, lin1_b, lin2_w, lin2_b, wf0, wf1, ws);
    hipLaunchKernelGGL(k_fuseout, dim3(256),     dim3(256), 0, stream,
                       fuse_w, fuse_b, bn_gamma, bn_beta, bn_mean, bn_var,
                       ws, out);
}